// Round 1
// baseline (1899.984 us; speedup 1.0000x reference)
//
#include <hip/hip_runtime.h>
#include <math.h>

#define N_NODES 50000
#define E_EDGES 1600000
#define F_IN    128
#define H_DIM   64
#define V_SIZE  16
#define OUT_DIM 2
#define EPS_F   1e-16f

__device__ __forceinline__ void atomicMaxF(float* addr, float val) {
    // works for any mix of pos/neg when addr initialized to -inf
    if (val >= 0.f) atomicMax((int*)addr, __float_as_int(val));
    else            atomicMin((unsigned int*)addr, __float_as_uint(val));
}

// ---------------- te = edge_emb @ We  (two [16,64] tables) ----------------
__global__ void table_kernel(const float* __restrict__ edge_emb,
                             const float* __restrict__ We1,
                             const float* __restrict__ We2,
                             float* __restrict__ te1, float* __restrict__ te2) {
    int t = blockIdx.x * blockDim.x + threadIdx.x;   // 0..2047
    if (t >= 2 * V_SIZE * H_DIM) return;
    int which = t >> 10;
    int idx = t & 1023;
    int v = idx >> 6, h = idx & 63;
    const float* We = which ? We2 : We1;
    float* te = which ? te2 : te1;
    float acc = 0.f;
    for (int k = 0; k < H_DIM; ++k)
        acc += edge_emb[v * H_DIM + k] * We[k * H_DIM + h];
    te[idx] = acc;
}

// ---------------- fused Q/K/V/Skip GEMM: [N,DIN] x [DIN,64] x4 ----------------
template <int DIN>
__global__ void qkvs_kernel(const float* __restrict__ X,
                            const float* __restrict__ Wq, const float* __restrict__ bq,
                            const float* __restrict__ Wk, const float* __restrict__ bk,
                            const float* __restrict__ Wv, const float* __restrict__ bv,
                            const float* __restrict__ Ws, const float* __restrict__ bs,
                            float* __restrict__ Q, float* __restrict__ K,
                            float* __restrict__ V, float* __restrict__ S) {
    __shared__ float xs[4][DIN];
    int row0 = blockIdx.x * 4;
    int tid = threadIdx.x;
    for (int i = tid; i < 4 * DIN; i += 256) {
        int r = i / DIN, c = i % DIN;
        int row = row0 + r;
        xs[r][c] = (row < N_NODES) ? X[row * DIN + c] : 0.f;
    }
    __syncthreads();
    int r = tid >> 6, c = tid & 63;
    int row = row0 + r;
    if (row >= N_NODES) return;
    float aq = bq[c], ak = bk[c], av = bv[c], as_ = bs[c];
    #pragma unroll 8
    for (int k = 0; k < DIN; ++k) {
        float xv = xs[r][k];
        aq  += xv * Wq[k * 64 + c];
        ak  += xv * Wk[k * 64 + c];
        av  += xv * Wv[k * 64 + c];
        as_ += xv * Ws[k * 64 + c];
    }
    Q[row * 64 + c] = aq;
    K[row * 64 + c] = ak;
    V[row * 64 + c] = av;
    S[row * 64 + c] = as_;
}

// ---------------- per-conv state init ----------------
__global__ void init_kernel(float* __restrict__ amax, float* __restrict__ denom,
                            float* __restrict__ num) {
    int i = blockIdx.x * blockDim.x + threadIdx.x;
    if (i < N_NODES) { amax[i] = -INFINITY; denom[i] = 0.f; }
    if (i < N_NODES * 64) num[i] = 0.f;
}

// ---------------- edge pass 1: alpha + segment max ----------------
__global__ void edge_alpha_kernel(const int* __restrict__ ei,
                                  const int* __restrict__ attr,
                                  const float* __restrict__ Q,
                                  const float* __restrict__ K,
                                  const float* __restrict__ te,
                                  float* __restrict__ alpha,
                                  float* __restrict__ amax) {
    int e = blockIdx.x * 4 + (threadIdx.x >> 6);
    if (e >= E_EDGES) return;
    int lane = threadIdx.x & 63;
    int src = ei[e], dst = ei[E_EDGES + e];
    int a = attr[e];
    float q = Q[dst * 64 + lane];
    float k = K[src * 64 + lane] + te[a * 64 + lane];
    float p = q * k;
    #pragma unroll
    for (int off = 32; off; off >>= 1) p += __shfl_xor(p, off);
    if (lane == 0) {
        p *= 0.125f;                       // 1/sqrt(64)
        alpha[e] = p;
        atomicMaxF(&amax[dst], p);
    }
}

// ---------------- edge pass 2: exp + scatter numerator/denominator ----------------
__global__ void edge_accum_kernel(const int* __restrict__ ei,
                                  const int* __restrict__ attr,
                                  const float* __restrict__ V,
                                  const float* __restrict__ te,
                                  const float* __restrict__ alpha,
                                  const float* __restrict__ amax,
                                  float* __restrict__ denom,
                                  float* __restrict__ num) {
    int e = blockIdx.x * 4 + (threadIdx.x >> 6);
    if (e >= E_EDGES) return;
    int lane = threadIdx.x & 63;
    int src = ei[e], dst = ei[E_EDGES + e];
    int a = attr[e];
    float ea = __expf(alpha[e] - amax[dst]);
    float m = ea * (V[src * 64 + lane] + te[a * 64 + lane]);
    atomicAdd(&num[dst * 64 + lane], m);
    if (lane == 0) atomicAdd(&denom[dst], ea);
}

// ---------------- node epilogue: normalize + skip + relu ----------------
__global__ void node_finish_kernel(const float* __restrict__ num,
                                   const float* __restrict__ denom,
                                   const float* __restrict__ S,
                                   float* __restrict__ Hout) {
    int i = blockIdx.x * blockDim.x + threadIdx.x;
    if (i >= N_NODES * 64) return;
    int node = i >> 6;
    float v = num[i] / (denom[node] + EPS_F) + S[i];
    Hout[i] = v > 0.f ? v : 0.f;
}

// ---------------- final projection [N,64] x [64,2] ----------------
__global__ void out_kernel(const float* __restrict__ Hf,
                           const float* __restrict__ Wout,
                           const float* __restrict__ bout,
                           float* __restrict__ out) {
    int i = blockIdx.x * blockDim.x + threadIdx.x;
    if (i >= N_NODES) return;
    float a0 = bout[0], a1 = bout[1];
    #pragma unroll 8
    for (int k = 0; k < 64; ++k) {
        float h = Hf[i * 64 + k];
        a0 += h * Wout[k * 2 + 0];
        a1 += h * Wout[k * 2 + 1];
    }
    out[i * 2 + 0] = a0;
    out[i * 2 + 1] = a1;
}

extern "C" void kernel_launch(void* const* d_in, const int* in_sizes, int n_in,
                              void* d_out, int out_size, void* d_ws, size_t ws_size,
                              hipStream_t stream) {
    const float* x        = (const float*)d_in[0];
    const int*   ei       = (const int*)  d_in[1];   // [2,E]: src then dst
    const int*   attr     = (const int*)  d_in[2];
    const float* edge_emb = (const float*)d_in[3];

    const float* c1_Wq = (const float*)d_in[4];  const float* c1_bq = (const float*)d_in[5];
    const float* c1_Wk = (const float*)d_in[6];  const float* c1_bk = (const float*)d_in[7];
    const float* c1_Wv = (const float*)d_in[8];  const float* c1_bv = (const float*)d_in[9];
    const float* c1_We = (const float*)d_in[10];
    const float* c1_Ws = (const float*)d_in[11]; const float* c1_bs = (const float*)d_in[12];

    const float* c2_Wq = (const float*)d_in[13]; const float* c2_bq = (const float*)d_in[14];
    const float* c2_Wk = (const float*)d_in[15]; const float* c2_bk = (const float*)d_in[16];
    const float* c2_Wv = (const float*)d_in[17]; const float* c2_bv = (const float*)d_in[18];
    const float* c2_We = (const float*)d_in[19];
    const float* c2_Ws = (const float*)d_in[20]; const float* c2_bs = (const float*)d_in[21];

    const float* Wout = (const float*)d_in[22];
    const float* bout = (const float*)d_in[23];

    float* w = (float*)d_ws;
    float* te1   = w;                       // 1024
    float* te2   = te1 + 1024;              // 1024
    float* Q     = te2 + 1024;              // N*64
    float* K     = Q + N_NODES * 64;
    float* Vb    = K + N_NODES * 64;
    float* S     = Vb + N_NODES * 64;
    float* alpha = S + N_NODES * 64;        // E
    float* amax  = alpha + E_EDGES;         // N
    float* denom = amax + N_NODES;          // N
    float* num   = denom + N_NODES;         // N*64
    float* H1    = num + N_NODES * 64;      // N*64 (conv1 out; conv2 out aliases here)

    const int edge_blocks = (E_EDGES + 3) / 4;
    const int node_blocks = (N_NODES * 64 + 255) / 256;
    const int row_blocks  = (N_NODES + 3) / 4;

    // edge-type tables for both convs
    table_kernel<<<8, 256, 0, stream>>>(edge_emb, c1_We, c2_We, te1, te2);

    // ---- conv1 ----
    qkvs_kernel<F_IN><<<row_blocks, 256, 0, stream>>>(
        x, c1_Wq, c1_bq, c1_Wk, c1_bk, c1_Wv, c1_bv, c1_Ws, c1_bs, Q, K, Vb, S);
    init_kernel<<<node_blocks, 256, 0, stream>>>(amax, denom, num);
    edge_alpha_kernel<<<edge_blocks, 256, 0, stream>>>(ei, attr, Q, K, te1, alpha, amax);
    edge_accum_kernel<<<edge_blocks, 256, 0, stream>>>(ei, attr, Vb, te1, alpha, amax, denom, num);
    node_finish_kernel<<<node_blocks, 256, 0, stream>>>(num, denom, S, H1);

    // ---- conv2 ----
    qkvs_kernel<H_DIM><<<row_blocks, 256, 0, stream>>>(
        H1, c2_Wq, c2_bq, c2_Wk, c2_bk, c2_Wv, c2_bv, c2_Ws, c2_bs, Q, K, Vb, S);
    init_kernel<<<node_blocks, 256, 0, stream>>>(amax, denom, num);
    edge_alpha_kernel<<<edge_blocks, 256, 0, stream>>>(ei, attr, Q, K, te2, alpha, amax);
    edge_accum_kernel<<<edge_blocks, 256, 0, stream>>>(ei, attr, Vb, te2, alpha, amax, denom, num);
    node_finish_kernel<<<node_blocks, 256, 0, stream>>>(num, denom, S, H1);  // H2 aliases H1

    // ---- output projection ----
    out_kernel<<<(N_NODES + 255) / 256, 256, 0, stream>>>(H1, Wout, bout, (float*)d_out);
}

// Round 2
// 1011.805 us; speedup vs baseline: 1.8778x; 1.8778x over previous
//
#include <hip/hip_runtime.h>
#include <math.h>

#define N_NODES 50000
#define E_EDGES 1600000
#define F_IN    128
#define H_DIM   64
#define V_SIZE  16
#define OUT_DIM 2
#define EPS_F   1e-16f

#define NB_SCAN 196   // ceil(50000/256)

// ---------------- te = edge_emb @ We  (two [16,64] tables) ----------------
__global__ void table_kernel(const float* __restrict__ edge_emb,
                             const float* __restrict__ We1,
                             const float* __restrict__ We2,
                             float* __restrict__ te1, float* __restrict__ te2) {
    int t = blockIdx.x * blockDim.x + threadIdx.x;   // 0..2047
    if (t >= 2 * V_SIZE * H_DIM) return;
    int which = t >> 10;
    int idx = t & 1023;
    int v = idx >> 6, h = idx & 63;
    const float* We = which ? We2 : We1;
    float* te = which ? te2 : te1;
    float acc = 0.f;
    for (int k = 0; k < H_DIM; ++k)
        acc += edge_emb[v * H_DIM + k] * We[k * H_DIM + h];
    te[idx] = acc;
}

// ---------------- CSR build: counting sort of edges by dst ----------------
__global__ void zero_deg_kernel(int* __restrict__ deg) {
    int i = blockIdx.x * blockDim.x + threadIdx.x;
    if (i < N_NODES) deg[i] = 0;
}

__global__ void hist_kernel(const int* __restrict__ ei, int* __restrict__ deg) {
    int e = blockIdx.x * blockDim.x + threadIdx.x;
    if (e >= E_EDGES) return;
    atomicAdd(&deg[ei[E_EDGES + e]], 1);
}

__global__ void scan1_kernel(const int* __restrict__ deg,
                             int* __restrict__ loc, int* __restrict__ bsum) {
    __shared__ int s[256];
    int i = blockIdx.x * 256 + threadIdx.x;
    int v = (i < N_NODES) ? deg[i] : 0;
    s[threadIdx.x] = v;
    __syncthreads();
    for (int off = 1; off < 256; off <<= 1) {
        int t = (threadIdx.x >= off) ? s[threadIdx.x - off] : 0;
        __syncthreads();
        s[threadIdx.x] += t;
        __syncthreads();
    }
    if (i < N_NODES) loc[i] = s[threadIdx.x] - v;   // exclusive
    if (threadIdx.x == 255) bsum[blockIdx.x] = s[255];
}

__global__ void scan2_kernel(const int* __restrict__ bsum, int* __restrict__ bpre) {
    __shared__ int s[256];
    int t = threadIdx.x;
    int v = (t < NB_SCAN) ? bsum[t] : 0;
    s[t] = v;
    __syncthreads();
    for (int off = 1; off < 256; off <<= 1) {
        int u = (t >= off) ? s[t - off] : 0;
        __syncthreads();
        s[t] += u;
        __syncthreads();
    }
    if (t < NB_SCAN) bpre[t] = s[t] - v;            // exclusive
}

__global__ void scan3_kernel(const int* __restrict__ loc, const int* __restrict__ bpre,
                             int* __restrict__ rowptr, int* __restrict__ cursor) {
    int i = blockIdx.x * 256 + threadIdx.x;
    if (i < N_NODES) {
        int r = loc[i] + bpre[blockIdx.x];
        rowptr[i] = r;
        cursor[i] = r;
    }
    if (i == 0) rowptr[N_NODES] = E_EDGES;
}

__global__ void scatter_kernel(const int* __restrict__ ei, const int* __restrict__ attr,
                               int* __restrict__ cursor, unsigned* __restrict__ epack) {
    int e = blockIdx.x * blockDim.x + threadIdx.x;
    if (e >= E_EDGES) return;
    int dst = ei[E_EDGES + e];
    int pos = atomicAdd(&cursor[dst], 1);
    epack[pos] = (unsigned)ei[e] | ((unsigned)attr[e] << 20);
}

// ---------------- fused Q/K/V/Skip GEMM: [N,DIN] x [DIN,64] x4 ----------------
template <int DIN>
__global__ void qkvs_kernel(const float* __restrict__ X,
                            const float* __restrict__ Wq, const float* __restrict__ bq,
                            const float* __restrict__ Wk, const float* __restrict__ bk,
                            const float* __restrict__ Wv, const float* __restrict__ bv,
                            const float* __restrict__ Ws, const float* __restrict__ bs,
                            float* __restrict__ Q, float* __restrict__ K,
                            float* __restrict__ V, float* __restrict__ S) {
    __shared__ float xs[4][DIN];
    int row0 = blockIdx.x * 4;
    int tid = threadIdx.x;
    for (int i = tid; i < 4 * DIN; i += 256) {
        int r = i / DIN, c = i % DIN;
        int row = row0 + r;
        xs[r][c] = (row < N_NODES) ? X[row * DIN + c] : 0.f;
    }
    __syncthreads();
    int r = tid >> 6, c = tid & 63;
    int row = row0 + r;
    if (row >= N_NODES) return;
    float aq = bq[c], ak = bk[c], av = bv[c], as_ = bs[c];
    #pragma unroll 8
    for (int k = 0; k < DIN; ++k) {
        float xv = xs[r][k];
        aq  += xv * Wq[k * 64 + c];
        ak  += xv * Wk[k * 64 + c];
        av  += xv * Wv[k * 64 + c];
        as_ += xv * Ws[k * 64 + c];
    }
    Q[row * 64 + c] = aq;
    K[row * 64 + c] = ak;
    V[row * 64 + c] = av;
    S[row * 64 + c] = as_;
}

// ---------------- per-node fused attention (gather-side, online softmax) ----------------
__global__ void conv_node_kernel(const int* __restrict__ rowptr,
                                 const unsigned* __restrict__ epack,
                                 const float* __restrict__ Q, const float* __restrict__ K,
                                 const float* __restrict__ V, const float* __restrict__ S,
                                 const float* __restrict__ te,
                                 float* __restrict__ Hout) {
    __shared__ float tes[V_SIZE * 64];
    for (int i = threadIdx.x; i < V_SIZE * 64; i += 256) tes[i] = te[i];
    __syncthreads();
    int node = blockIdx.x * 4 + (threadIdx.x >> 6);
    if (node >= N_NODES) return;
    int lane = threadIdx.x & 63;
    int e0 = rowptr[node], e1 = rowptr[node + 1];
    float q = Q[node * 64 + lane];
    float m = -INFINITY, den = 0.f, acc = 0.f;
    for (int e = e0; e < e1; ++e) {
        unsigned p = epack[e];
        int src = p & 0xFFFFF;
        int a = p >> 20;
        float tev = tes[a * 64 + lane];
        float kv = K[src * 64 + lane] + tev;
        float t = q * kv;
        #pragma unroll
        for (int off = 32; off; off >>= 1) t += __shfl_xor(t, off);
        t *= 0.125f;                                   // 1/sqrt(64)
        if (t > m) {                                   // wave-uniform branch
            float sc = __expf(m - t);
            acc *= sc; den *= sc; m = t;
        }
        float ea = __expf(t - m);
        float vv = V[src * 64 + lane] + tev;
        acc = fmaf(ea, vv, acc);
        den += ea;
    }
    float o = acc / (den + EPS_F) + S[node * 64 + lane];
    Hout[node * 64 + lane] = o > 0.f ? o : 0.f;
}

// ---------------- final projection [N,64] x [64,2] ----------------
__global__ void out_kernel(const float* __restrict__ Hf,
                           const float* __restrict__ Wout,
                           const float* __restrict__ bout,
                           float* __restrict__ out) {
    int i = blockIdx.x * blockDim.x + threadIdx.x;
    if (i >= N_NODES) return;
    float a0 = bout[0], a1 = bout[1];
    #pragma unroll 8
    for (int k = 0; k < 64; ++k) {
        float h = Hf[i * 64 + k];
        a0 += h * Wout[k * 2 + 0];
        a1 += h * Wout[k * 2 + 1];
    }
    out[i * 2 + 0] = a0;
    out[i * 2 + 1] = a1;
}

extern "C" void kernel_launch(void* const* d_in, const int* in_sizes, int n_in,
                              void* d_out, int out_size, void* d_ws, size_t ws_size,
                              hipStream_t stream) {
    const float* x        = (const float*)d_in[0];
    const int*   ei       = (const int*)  d_in[1];   // [2,E]: src row then dst row
    const int*   attr     = (const int*)  d_in[2];
    const float* edge_emb = (const float*)d_in[3];

    const float* c1_Wq = (const float*)d_in[4];  const float* c1_bq = (const float*)d_in[5];
    const float* c1_Wk = (const float*)d_in[6];  const float* c1_bk = (const float*)d_in[7];
    const float* c1_Wv = (const float*)d_in[8];  const float* c1_bv = (const float*)d_in[9];
    const float* c1_We = (const float*)d_in[10];
    const float* c1_Ws = (const float*)d_in[11]; const float* c1_bs = (const float*)d_in[12];

    const float* c2_Wq = (const float*)d_in[13]; const float* c2_bq = (const float*)d_in[14];
    const float* c2_Wk = (const float*)d_in[15]; const float* c2_bk = (const float*)d_in[16];
    const float* c2_Wv = (const float*)d_in[17]; const float* c2_bv = (const float*)d_in[18];
    const float* c2_We = (const float*)d_in[19];
    const float* c2_Ws = (const float*)d_in[20]; const float* c2_bs = (const float*)d_in[21];

    const float* Wout = (const float*)d_in[22];
    const float* bout = (const float*)d_in[23];

    // -------- workspace carve-up --------
    float* w = (float*)d_ws;
    float* te1 = w;                         // 1024
    float* te2 = te1 + 1024;                // 1024
    float* Q   = te2 + 1024;                // N*64
    float* K   = Q  + N_NODES * 64;
    float* Vb  = K  + N_NODES * 64;
    float* S   = Vb + N_NODES * 64;
    float* H1  = S  + N_NODES * 64;         // conv out (conv2 aliases)
    int*   ip  = (int*)(H1 + N_NODES * 64);
    int* deg    = ip;                       // N
    int* loc    = deg + N_NODES;            // N
    int* bsum   = loc + N_NODES;            // NB_SCAN
    int* bpre   = bsum + NB_SCAN;           // NB_SCAN
    int* rowptr = bpre + NB_SCAN;           // N+1
    int* cursor = rowptr + N_NODES + 1;     // N
    unsigned* epack = (unsigned*)(cursor + N_NODES);  // E

    const int edge_blocks = (E_EDGES + 255) / 256;
    const int node_grp    = (N_NODES + 3) / 4;

    // edge-type tables for both convs
    table_kernel<<<8, 256, 0, stream>>>(edge_emb, c1_We, c2_We, te1, te2);

    // -------- CSR build (counting sort by dst) --------
    zero_deg_kernel<<<NB_SCAN, 256, 0, stream>>>(deg);
    hist_kernel<<<edge_blocks, 256, 0, stream>>>(ei, deg);
    scan1_kernel<<<NB_SCAN, 256, 0, stream>>>(deg, loc, bsum);
    scan2_kernel<<<1, 256, 0, stream>>>(bsum, bpre);
    scan3_kernel<<<NB_SCAN, 256, 0, stream>>>(loc, bpre, rowptr, cursor);
    scatter_kernel<<<edge_blocks, 256, 0, stream>>>(ei, attr, cursor, epack);

    // -------- conv1 --------
    qkvs_kernel<F_IN><<<node_grp, 256, 0, stream>>>(
        x, c1_Wq, c1_bq, c1_Wk, c1_bk, c1_Wv, c1_bv, c1_Ws, c1_bs, Q, K, Vb, S);
    conv_node_kernel<<<node_grp, 256, 0, stream>>>(rowptr, epack, Q, K, Vb, S, te1, H1);

    // -------- conv2 --------
    qkvs_kernel<H_DIM><<<node_grp, 256, 0, stream>>>(
        H1, c2_Wq, c2_bq, c2_Wk, c2_bk, c2_Wv, c2_bv, c2_Ws, c2_bs, Q, K, Vb, S);
    conv_node_kernel<<<node_grp, 256, 0, stream>>>(rowptr, epack, Q, K, Vb, S, te2, H1);

    // -------- output projection --------
    out_kernel<<<(N_NODES + 255) / 256, 256, 0, stream>>>(H1, Wout, bout, (float*)d_out);
}

// Round 5
// 631.454 us; speedup vs baseline: 3.0089x; 1.6023x over previous
//
#include <hip/hip_runtime.h>
#include <math.h>

#define N_NODES 50000
#define E_EDGES 1600000
#define F_IN    128
#define H_DIM   64
#define V_SIZE  16
#define OUT_DIM 2
#define EPS_F   1e-16f

#define NB_SCAN 196   // ceil(50000/256)

// ---------------- te = edge_emb @ We  (two [16,64] tables) ----------------
__global__ void table_kernel(const float* __restrict__ edge_emb,
                             const float* __restrict__ We1,
                             const float* __restrict__ We2,
                             float* __restrict__ te1, float* __restrict__ te2) {
    int t = blockIdx.x * blockDim.x + threadIdx.x;   // 0..2047
    if (t >= 2 * V_SIZE * H_DIM) return;
    int which = t >> 10;
    int idx = t & 1023;
    int v = idx >> 6, h = idx & 63;
    const float* We = which ? We2 : We1;
    float* te = which ? te2 : te1;
    float acc = 0.f;
    for (int k = 0; k < H_DIM; ++k)
        acc += edge_emb[v * H_DIM + k] * We[k * H_DIM + h];
    te[idx] = acc;
}

// ---------------- CSR build: counting sort of edges by dst ----------------
__global__ void zero_deg_kernel(int* __restrict__ deg) {
    int i = blockIdx.x * blockDim.x + threadIdx.x;
    if (i < N_NODES) deg[i] = 0;
}

__global__ void hist_kernel(const int* __restrict__ ei, int* __restrict__ deg) {
    int e = blockIdx.x * blockDim.x + threadIdx.x;
    if (e >= E_EDGES) return;
    atomicAdd(&deg[ei[E_EDGES + e]], 1);
}

__global__ void scan1_kernel(const int* __restrict__ deg,
                             int* __restrict__ loc, int* __restrict__ bsum) {
    __shared__ int s[256];
    int i = blockIdx.x * 256 + threadIdx.x;
    int v = (i < N_NODES) ? deg[i] : 0;
    s[threadIdx.x] = v;
    __syncthreads();
    for (int off = 1; off < 256; off <<= 1) {
        int t = (threadIdx.x >= off) ? s[threadIdx.x - off] : 0;
        __syncthreads();
        s[threadIdx.x] += t;
        __syncthreads();
    }
    if (i < N_NODES) loc[i] = s[threadIdx.x] - v;   // exclusive
    if (threadIdx.x == 255) bsum[blockIdx.x] = s[255];
}

__global__ void scan2_kernel(const int* __restrict__ bsum, int* __restrict__ bpre) {
    __shared__ int s[256];
    int t = threadIdx.x;
    int v = (t < NB_SCAN) ? bsum[t] : 0;
    s[t] = v;
    __syncthreads();
    for (int off = 1; off < 256; off <<= 1) {
        int u = (t >= off) ? s[t - off] : 0;
        __syncthreads();
        s[t] += u;
        __syncthreads();
    }
    if (t < NB_SCAN) bpre[t] = s[t] - v;            // exclusive
}

__global__ void scan3_kernel(const int* __restrict__ loc, const int* __restrict__ bpre,
                             int* __restrict__ rowptr, int* __restrict__ cursor) {
    int i = blockIdx.x * 256 + threadIdx.x;
    if (i < N_NODES) {
        int r = loc[i] + bpre[blockIdx.x];
        rowptr[i] = r;
        cursor[i] = r;
    }
    if (i == 0) rowptr[N_NODES] = E_EDGES;
}

__global__ void scatter_kernel(const int* __restrict__ ei, const int* __restrict__ attr,
                               int* __restrict__ cursor, unsigned* __restrict__ epack) {
    int e = blockIdx.x * blockDim.x + threadIdx.x;
    if (e >= E_EDGES) return;
    int dst = ei[E_EDGES + e];
    int pos = atomicAdd(&cursor[dst], 1);
    epack[pos] = (unsigned)ei[e] | ((unsigned)attr[e] << 20);
}

// ------- fused Q/K/V/Skip GEMM: 32 rows/block, 32 accumulators/thread -------
template <int DIN>
__global__ __launch_bounds__(256) void qkvs_kernel(
        const float* __restrict__ X,
        const float* __restrict__ Wq, const float* __restrict__ bq,
        const float* __restrict__ Wk, const float* __restrict__ bk,
        const float* __restrict__ Wv, const float* __restrict__ bv,
        const float* __restrict__ Ws, const float* __restrict__ bs,
        float* __restrict__ Q, float* __restrict__ K,
        float* __restrict__ V, float* __restrict__ S) {
    __shared__ float xs[32][DIN];
    const int row0 = blockIdx.x * 32;
    const int tid = threadIdx.x;
    const int f4_per_row = DIN / 4;
    const int nf4 = 32 * f4_per_row;
    for (int i = tid; i < nf4; i += 256) {
        int row = row0 + i / f4_per_row;
        float4 v = make_float4(0.f, 0.f, 0.f, 0.f);
        if (row < N_NODES) v = ((const float4*)X)[(size_t)row0 * f4_per_row + i];
        ((float4*)&xs[0][0])[i] = v;
    }
    __syncthreads();
    const int c = tid & 63;        // output column
    const int w = tid >> 6;        // wave id: rows w, w+4, ..., w+28
    float aq[8], ak[8], av[8], as_[8];
    float bq_ = bq[c], bk_ = bk[c], bv_ = bv[c], bs_ = bs[c];
    #pragma unroll
    for (int j = 0; j < 8; ++j) { aq[j] = bq_; ak[j] = bk_; av[j] = bv_; as_[j] = bs_; }
    #pragma unroll 2
    for (int k = 0; k < DIN; ++k) {
        float wq = Wq[k * 64 + c], wk = Wk[k * 64 + c];
        float wv = Wv[k * 64 + c], ws = Ws[k * 64 + c];
        #pragma unroll
        for (int j = 0; j < 8; ++j) {
            float xv = xs[w + j * 4][k];
            aq[j]  = fmaf(xv, wq, aq[j]);
            ak[j]  = fmaf(xv, wk, ak[j]);
            av[j]  = fmaf(xv, wv, av[j]);
            as_[j] = fmaf(xv, ws, as_[j]);
        }
    }
    #pragma unroll
    for (int j = 0; j < 8; ++j) {
        int row = row0 + w + j * 4;
        if (row < N_NODES) {
            Q[row * 64 + c] = aq[j];
            K[row * 64 + c] = ak[j];
            V[row * 64 + c] = av[j];
            S[row * 64 + c] = as_[j];
        }
    }
}

// ------- per-node attention: 4 edges/wave, float4 lanes, no-max softmax -------
__global__ __launch_bounds__(256) void conv_node_kernel(
        const int* __restrict__ rowptr, const unsigned* __restrict__ epack,
        const float* __restrict__ Q, const float* __restrict__ K,
        const float* __restrict__ V, const float* __restrict__ S,
        const float* __restrict__ te, float* __restrict__ Hout) {
    __shared__ float4 tes[V_SIZE * 16];
    for (int i = threadIdx.x; i < V_SIZE * 16; i += 256)
        tes[i] = ((const float4*)te)[i];
    __syncthreads();
    int node = blockIdx.x * 4 + (threadIdx.x >> 6);
    if (node >= N_NODES) return;
    int lane = threadIdx.x & 63;
    int quarter = lane >> 4;       // which of 4 concurrent edges
    int lq = lane & 15;            // channel group: ch = lq*4 .. lq*4+3
    int e0 = rowptr[node], e1 = rowptr[node + 1];
    float4 q = ((const float4*)Q)[node * 16 + lq];
    float4 acc = make_float4(0.f, 0.f, 0.f, 0.f);
    float den = 0.f;
    #pragma unroll 2
    for (int eb = e0; eb < e1; eb += 4) {
        int e = eb + quarter;
        bool valid = e < e1;
        unsigned p = valid ? epack[e] : 0u;
        int src = p & 0xFFFFF;
        int a = p >> 20;
        float4 tev = tes[a * 16 + lq];
        float4 kv = ((const float4*)K)[src * 16 + lq];
        float t = q.x * (kv.x + tev.x) + q.y * (kv.y + tev.y)
                + q.z * (kv.z + tev.z) + q.w * (kv.w + tev.w);
        t += __shfl_xor(t, 1);
        t += __shfl_xor(t, 2);
        t += __shfl_xor(t, 4);
        t += __shfl_xor(t, 8);     // full dot over the quarter's 16 lanes
        float ea = valid ? __expf(t * 0.125f) : 0.f;   // no-max softmax (fp32-safe)
        float4 vv = ((const float4*)V)[src * 16 + lq];
        acc.x = fmaf(ea, vv.x + tev.x, acc.x);
        acc.y = fmaf(ea, vv.y + tev.y, acc.y);
        acc.z = fmaf(ea, vv.z + tev.z, acc.z);
        acc.w = fmaf(ea, vv.w + tev.w, acc.w);
        den += ea;
    }
    // cross-quarter reduction (same channels in all 4 quarters)
    #pragma unroll
    for (int off = 16; off < 64; off <<= 1) {
        acc.x += __shfl_xor(acc.x, off);
        acc.y += __shfl_xor(acc.y, off);
        acc.z += __shfl_xor(acc.z, off);
        acc.w += __shfl_xor(acc.w, off);
        den   += __shfl_xor(den, off);
    }
    if (quarter == 0) {
        float4 s4 = ((const float4*)S)[node * 16 + lq];
        float inv = 1.f / (den + EPS_F);
        float4 o;
        o.x = fmaxf(fmaf(acc.x, inv, s4.x), 0.f);
        o.y = fmaxf(fmaf(acc.y, inv, s4.y), 0.f);
        o.z = fmaxf(fmaf(acc.z, inv, s4.z), 0.f);
        o.w = fmaxf(fmaf(acc.w, inv, s4.w), 0.f);
        ((float4*)Hout)[node * 16 + lq] = o;
    }
}

// ---------------- final projection: 16 lanes per node, coalesced ----------------
__global__ void out_kernel(const float* __restrict__ Hf,
                           const float* __restrict__ Wout,
                           const float* __restrict__ bout,
                           float* __restrict__ out) {
    int node = blockIdx.x * 16 + (threadIdx.x >> 4);
    if (node >= N_NODES) return;
    int lq = threadIdx.x & 15;
    float4 h = ((const float4*)Hf)[node * 16 + lq];
    int k0 = lq * 4;
    float p0 = h.x * Wout[(k0 + 0) * 2] + h.y * Wout[(k0 + 1) * 2]
             + h.z * Wout[(k0 + 2) * 2] + h.w * Wout[(k0 + 3) * 2];
    float p1 = h.x * Wout[(k0 + 0) * 2 + 1] + h.y * Wout[(k0 + 1) * 2 + 1]
             + h.z * Wout[(k0 + 2) * 2 + 1] + h.w * Wout[(k0 + 3) * 2 + 1];
    #pragma unroll
    for (int off = 1; off < 16; off <<= 1) {
        p0 += __shfl_xor(p0, off);
        p1 += __shfl_xor(p1, off);
    }
    if (lq == 0) {
        out[node * 2 + 0] = p0 + bout[0];
        out[node * 2 + 1] = p1 + bout[1];
    }
}

extern "C" void kernel_launch(void* const* d_in, const int* in_sizes, int n_in,
                              void* d_out, int out_size, void* d_ws, size_t ws_size,
                              hipStream_t stream) {
    const float* x        = (const float*)d_in[0];
    const int*   ei       = (const int*)  d_in[1];   // [2,E]: src row then dst row
    const int*   attr     = (const int*)  d_in[2];
    const float* edge_emb = (const float*)d_in[3];

    const float* c1_Wq = (const float*)d_in[4];  const float* c1_bq = (const float*)d_in[5];
    const float* c1_Wk = (const float*)d_in[6];  const float* c1_bk = (const float*)d_in[7];
    const float* c1_Wv = (const float*)d_in[8];  const float* c1_bv = (const float*)d_in[9];
    const float* c1_We = (const float*)d_in[10];
    const float* c1_Ws = (const float*)d_in[11]; const float* c1_bs = (const float*)d_in[12];

    const float* c2_Wq = (const float*)d_in[13]; const float* c2_bq = (const float*)d_in[14];
    const float* c2_Wk = (const float*)d_in[15]; const float* c2_bk = (const float*)d_in[16];
    const float* c2_Wv = (const float*)d_in[17]; const float* c2_bv = (const float*)d_in[18];
    const float* c2_We = (const float*)d_in[19];
    const float* c2_Ws = (const float*)d_in[20]; const float* c2_bs = (const float*)d_in[21];

    const float* Wout = (const float*)d_in[22];
    const float* bout = (const float*)d_in[23];

    // -------- workspace carve-up --------
    float* w = (float*)d_ws;
    float* te1 = w;                         // 1024
    float* te2 = te1 + 1024;                // 1024
    float* Q   = te2 + 1024;                // N*64
    float* K   = Q  + N_NODES * 64;
    float* Vb  = K  + N_NODES * 64;
    float* S   = Vb + N_NODES * 64;
    float* H1  = S  + N_NODES * 64;         // conv out (conv2 aliases)
    int*   ip  = (int*)(H1 + N_NODES * 64);
    int* deg    = ip;                       // N
    int* loc    = deg + N_NODES;            // N
    int* bsum   = loc + N_NODES;            // NB_SCAN
    int* bpre   = bsum + NB_SCAN;           // NB_SCAN
    int* rowptr = bpre + NB_SCAN;           // N+1
    int* cursor = rowptr + N_NODES + 1;     // N
    unsigned* epack = (unsigned*)(cursor + N_NODES);  // E

    const int edge_blocks = (E_EDGES + 255) / 256;
    const int node_grp    = (N_NODES + 3) / 4;        // conv_node: 4 nodes/block
    const int gemm_blocks = (N_NODES + 31) / 32;      // qkvs: 32 rows/block

    // edge-type tables for both convs
    table_kernel<<<8, 256, 0, stream>>>(edge_emb, c1_We, c2_We, te1, te2);

    // -------- CSR build (counting sort by dst) --------
    zero_deg_kernel<<<NB_SCAN, 256, 0, stream>>>(deg);
    hist_kernel<<<edge_blocks, 256, 0, stream>>>(ei, deg);
    scan1_kernel<<<NB_SCAN, 256, 0, stream>>>(deg, loc, bsum);
    scan2_kernel<<<1, 256, 0, stream>>>(bsum, bpre);
    scan3_kernel<<<NB_SCAN, 256, 0, stream>>>(loc, bpre, rowptr, cursor);
    scatter_kernel<<<edge_blocks, 256, 0, stream>>>(ei, attr, cursor, epack);

    // -------- conv1 --------
    qkvs_kernel<F_IN><<<gemm_blocks, 256, 0, stream>>>(
        x, c1_Wq, c1_bq, c1_Wk, c1_bk, c1_Wv, c1_bv, c1_Ws, c1_bs, Q, K, Vb, S);
    conv_node_kernel<<<node_grp, 256, 0, stream>>>(rowptr, epack, Q, K, Vb, S, te1, H1);

    // -------- conv2 --------
    qkvs_kernel<H_DIM><<<gemm_blocks, 256, 0, stream>>>(
        H1, c2_Wq, c2_bq, c2_Wk, c2_bk, c2_Wv, c2_bv, c2_Ws, c2_bs, Q, K, Vb, S);
    conv_node_kernel<<<node_grp, 256, 0, stream>>>(rowptr, epack, Q, K, Vb, S, te2, H1);

    // -------- output projection --------
    out_kernel<<<(N_NODES + 15) / 16, 256, 0, stream>>>(H1, Wout, bout, (float*)d_out);
}

// Round 6
// 582.143 us; speedup vs baseline: 3.2638x; 1.0847x over previous
//
#include <hip/hip_runtime.h>
#include <math.h>

#define N_NODES 50000
#define E_EDGES 1600000
#define F_IN    128
#define H_DIM   64
#define V_SIZE  16
#define OUT_DIM 2
#define EPS_F   1e-16f

#define NB_SCAN 196   // ceil(50000/256)
#define NBKT    196   // ceil(50000/256) coarse buckets (256 nodes each)
#define EPB     4096  // edges per bin_kernel block

// ---------------- te = edge_emb @ We  (two [16,64] tables) ----------------
__global__ void table_kernel(const float* __restrict__ edge_emb,
                             const float* __restrict__ We1,
                             const float* __restrict__ We2,
                             float* __restrict__ te1, float* __restrict__ te2) {
    int t = blockIdx.x * blockDim.x + threadIdx.x;   // 0..2047
    if (t >= 2 * V_SIZE * H_DIM) return;
    int which = t >> 10;
    int idx = t & 1023;
    int v = idx >> 6, h = idx & 63;
    const float* We = which ? We2 : We1;
    float* te = which ? te2 : te1;
    float acc = 0.f;
    for (int k = 0; k < H_DIM; ++k)
        acc += edge_emb[v * H_DIM + k] * We[k * H_DIM + h];
    te[idx] = acc;
}

// ---------------- CSR build: counting sort of edges by dst ----------------
__global__ void zero_deg_kernel(int* __restrict__ deg) {
    int i = blockIdx.x * blockDim.x + threadIdx.x;
    if (i < N_NODES) deg[i] = 0;
}

__global__ void hist_kernel(const int* __restrict__ ei, int* __restrict__ deg) {
    int e = blockIdx.x * blockDim.x + threadIdx.x;
    if (e >= E_EDGES) return;
    atomicAdd(&deg[ei[E_EDGES + e]], 1);
}

__global__ void scan1_kernel(const int* __restrict__ deg,
                             int* __restrict__ loc, int* __restrict__ bsum) {
    __shared__ int s[256];
    int i = blockIdx.x * 256 + threadIdx.x;
    int v = (i < N_NODES) ? deg[i] : 0;
    s[threadIdx.x] = v;
    __syncthreads();
    for (int off = 1; off < 256; off <<= 1) {
        int t = (threadIdx.x >= off) ? s[threadIdx.x - off] : 0;
        __syncthreads();
        s[threadIdx.x] += t;
        __syncthreads();
    }
    if (i < N_NODES) loc[i] = s[threadIdx.x] - v;   // exclusive
    if (threadIdx.x == 255) bsum[blockIdx.x] = s[255];
}

__global__ void scan2_kernel(const int* __restrict__ bsum, int* __restrict__ bpre) {
    __shared__ int s[256];
    int t = threadIdx.x;
    int v = (t < NB_SCAN) ? bsum[t] : 0;
    s[t] = v;
    __syncthreads();
    for (int off = 1; off < 256; off <<= 1) {
        int u = (t >= off) ? s[t - off] : 0;
        __syncthreads();
        s[t] += u;
        __syncthreads();
    }
    if (t < NB_SCAN) bpre[t] = s[t] - v;            // exclusive
}

__global__ void scan3_kernel(const int* __restrict__ loc, const int* __restrict__ bpre,
                             int* __restrict__ rowptr, int* __restrict__ cursor,
                             int* __restrict__ bcur) {
    int i = blockIdx.x * 256 + threadIdx.x;
    if (i < N_NODES) {
        int r = loc[i] + bpre[blockIdx.x];
        rowptr[i] = r;
        cursor[i] = r;
        if ((i & 255) == 0) bcur[i >> 8] = r;        // coarse-bucket base/cursor
    }
    if (i == 0) rowptr[N_NODES] = E_EDGES;
}

// -------- pass A: bin edges by dst>>8 (coalesced-ish chunk writes) --------
__global__ __launch_bounds__(256) void bin_kernel(const int* __restrict__ ei,
                                                  const int* __restrict__ attr,
                                                  int* __restrict__ bcur,
                                                  unsigned* __restrict__ ebin) {
    __shared__ unsigned skey[EPB];
    __shared__ unsigned char sbkt[EPB];
    __shared__ int hist[NBKT], base[NBKT];
    const int tid = threadIdx.x;
    for (int i = tid; i < NBKT; i += 256) hist[i] = 0;
    __syncthreads();
    const int e0 = blockIdx.x * EPB;
    for (int i = tid; i < EPB; i += 256) {
        int e = e0 + i;
        if (e < E_EDGES) {
            int src = ei[e], dst = ei[E_EDGES + e], a = attr[e];
            skey[i] = (unsigned)src | ((unsigned)a << 16) | ((unsigned)(dst & 255) << 20);
            int b = dst >> 8;
            sbkt[i] = (unsigned char)b;
            atomicAdd(&hist[b], 1);
        } else {
            sbkt[i] = 0xFF;
        }
    }
    __syncthreads();
    for (int i = tid; i < NBKT; i += 256) {
        int h = hist[i];
        base[i] = h ? atomicAdd(&bcur[i], h) : 0;
        hist[i] = 0;                                  // reuse as rank counter
    }
    __syncthreads();
    for (int i = tid; i < EPB; i += 256) {
        int b = sbkt[i];
        if (b != 0xFF) {
            int r = atomicAdd(&hist[b], 1);
            ebin[base[b] + r] = skey[i];
        }
    }
}

// -------- pass B: exact placement within 32KB bucket windows (L2-resident) --------
__global__ __launch_bounds__(256) void place_kernel(const int* __restrict__ rowptr,
                                                    const unsigned* __restrict__ ebin,
                                                    int* __restrict__ cursor,
                                                    unsigned* __restrict__ epack) {
    int b = blockIdx.x;
    int n0 = b << 8;
    int n1 = n0 + 256; if (n1 > N_NODES) n1 = N_NODES;
    int bstart = rowptr[n0], bend = rowptr[n1];
    for (int e = bstart + blockIdx.y * 256 + threadIdx.x; e < bend; e += 256 * 8) {
        unsigned p = ebin[e];
        int dst = n0 + (int)((p >> 20) & 255u);
        int pos = atomicAdd(&cursor[dst], 1);
        epack[pos] = p;                               // src:16 | attr:4 (| dst_lo, unused)
    }
}

// ------- fused Q/K/V/Skip GEMM: 32 rows/block, 32 accumulators/thread -------
template <int DIN>
__global__ __launch_bounds__(256) void qkvs_kernel(
        const float* __restrict__ X,
        const float* __restrict__ Wq, const float* __restrict__ bq,
        const float* __restrict__ Wk, const float* __restrict__ bk,
        const float* __restrict__ Wv, const float* __restrict__ bv,
        const float* __restrict__ Ws, const float* __restrict__ bs,
        float* __restrict__ Q, float* __restrict__ K,
        float* __restrict__ V, float* __restrict__ S) {
    __shared__ float xs[32][DIN];
    const int row0 = blockIdx.x * 32;
    const int tid = threadIdx.x;
    const int f4_per_row = DIN / 4;
    const int nf4 = 32 * f4_per_row;
    for (int i = tid; i < nf4; i += 256) {
        int row = row0 + i / f4_per_row;
        float4 v = make_float4(0.f, 0.f, 0.f, 0.f);
        if (row < N_NODES) v = ((const float4*)X)[(size_t)row0 * f4_per_row + i];
        ((float4*)&xs[0][0])[i] = v;
    }
    __syncthreads();
    const int c = tid & 63;        // output column
    const int w = tid >> 6;        // wave id: rows w, w+4, ..., w+28
    float aq[8], ak[8], av[8], as_[8];
    float bq_ = bq[c], bk_ = bk[c], bv_ = bv[c], bs_ = bs[c];
    #pragma unroll
    for (int j = 0; j < 8; ++j) { aq[j] = bq_; ak[j] = bk_; av[j] = bv_; as_[j] = bs_; }
    #pragma unroll 2
    for (int k = 0; k < DIN; ++k) {
        float wq = Wq[k * 64 + c], wk = Wk[k * 64 + c];
        float wv = Wv[k * 64 + c], ws = Ws[k * 64 + c];
        #pragma unroll
        for (int j = 0; j < 8; ++j) {
            float xv = xs[w + j * 4][k];
            aq[j]  = fmaf(xv, wq, aq[j]);
            ak[j]  = fmaf(xv, wk, ak[j]);
            av[j]  = fmaf(xv, wv, av[j]);
            as_[j] = fmaf(xv, ws, as_[j]);
        }
    }
    #pragma unroll
    for (int j = 0; j < 8; ++j) {
        int row = row0 + w + j * 4;
        if (row < N_NODES) {
            Q[row * 64 + c] = aq[j];
            K[row * 64 + c] = ak[j];
            V[row * 64 + c] = av[j];
            S[row * 64 + c] = as_[j];
        }
    }
}

// ------- per-node attention: 4 edges/wave, float4 lanes, no-max softmax -------
__global__ __launch_bounds__(256) void conv_node_kernel(
        const int* __restrict__ rowptr, const unsigned* __restrict__ epack,
        const float* __restrict__ Q, const float* __restrict__ K,
        const float* __restrict__ V, const float* __restrict__ S,
        const float* __restrict__ te, float* __restrict__ Hout) {
    __shared__ float4 tes[V_SIZE * 16];
    for (int i = threadIdx.x; i < V_SIZE * 16; i += 256)
        tes[i] = ((const float4*)te)[i];
    __syncthreads();
    int node = blockIdx.x * 4 + (threadIdx.x >> 6);
    if (node >= N_NODES) return;
    int lane = threadIdx.x & 63;
    int quarter = lane >> 4;       // which of 4 concurrent edges
    int lq = lane & 15;            // channel group: ch = lq*4 .. lq*4+3
    int e0 = rowptr[node], e1 = rowptr[node + 1];
    float4 q = ((const float4*)Q)[node * 16 + lq];
    float4 acc = make_float4(0.f, 0.f, 0.f, 0.f);
    float den = 0.f;
    #pragma unroll 2
    for (int eb = e0; eb < e1; eb += 4) {
        int e = eb + quarter;
        bool valid = e < e1;
        unsigned p = valid ? epack[e] : 0u;
        int src = p & 0xFFFF;
        int a = (p >> 16) & 15;
        float4 tev = tes[a * 16 + lq];
        float4 kv = ((const float4*)K)[src * 16 + lq];
        float t = q.x * (kv.x + tev.x) + q.y * (kv.y + tev.y)
                + q.z * (kv.z + tev.z) + q.w * (kv.w + tev.w);
        t += __shfl_xor(t, 1);
        t += __shfl_xor(t, 2);
        t += __shfl_xor(t, 4);
        t += __shfl_xor(t, 8);     // full dot over the quarter's 16 lanes
        float ea = valid ? __expf(t * 0.125f) : 0.f;   // no-max softmax (fp32-safe)
        float4 vv = ((const float4*)V)[src * 16 + lq];
        acc.x = fmaf(ea, vv.x + tev.x, acc.x);
        acc.y = fmaf(ea, vv.y + tev.y, acc.y);
        acc.z = fmaf(ea, vv.z + tev.z, acc.z);
        acc.w = fmaf(ea, vv.w + tev.w, acc.w);
        den += ea;
    }
    // cross-quarter reduction (same channels in all 4 quarters)
    #pragma unroll
    for (int off = 16; off < 64; off <<= 1) {
        acc.x += __shfl_xor(acc.x, off);
        acc.y += __shfl_xor(acc.y, off);
        acc.z += __shfl_xor(acc.z, off);
        acc.w += __shfl_xor(acc.w, off);
        den   += __shfl_xor(den, off);
    }
    if (quarter == 0) {
        float4 s4 = ((const float4*)S)[node * 16 + lq];
        float inv = 1.f / (den + EPS_F);
        float4 o;
        o.x = fmaxf(fmaf(acc.x, inv, s4.x), 0.f);
        o.y = fmaxf(fmaf(acc.y, inv, s4.y), 0.f);
        o.z = fmaxf(fmaf(acc.z, inv, s4.z), 0.f);
        o.w = fmaxf(fmaf(acc.w, inv, s4.w), 0.f);
        ((float4*)Hout)[node * 16 + lq] = o;
    }
}

// ---------------- final projection: 16 lanes per node, coalesced ----------------
__global__ void out_kernel(const float* __restrict__ Hf,
                           const float* __restrict__ Wout,
                           const float* __restrict__ bout,
                           float* __restrict__ out) {
    int node = blockIdx.x * 16 + (threadIdx.x >> 4);
    if (node >= N_NODES) return;
    int lq = threadIdx.x & 15;
    float4 h = ((const float4*)Hf)[node * 16 + lq];
    int k0 = lq * 4;
    float p0 = h.x * Wout[(k0 + 0) * 2] + h.y * Wout[(k0 + 1) * 2]
             + h.z * Wout[(k0 + 2) * 2] + h.w * Wout[(k0 + 3) * 2];
    float p1 = h.x * Wout[(k0 + 0) * 2 + 1] + h.y * Wout[(k0 + 1) * 2 + 1]
             + h.z * Wout[(k0 + 2) * 2 + 1] + h.w * Wout[(k0 + 3) * 2 + 1];
    #pragma unroll
    for (int off = 1; off < 16; off <<= 1) {
        p0 += __shfl_xor(p0, off);
        p1 += __shfl_xor(p1, off);
    }
    if (lq == 0) {
        out[node * 2 + 0] = p0 + bout[0];
        out[node * 2 + 1] = p1 + bout[1];
    }
}

extern "C" void kernel_launch(void* const* d_in, const int* in_sizes, int n_in,
                              void* d_out, int out_size, void* d_ws, size_t ws_size,
                              hipStream_t stream) {
    const float* x        = (const float*)d_in[0];
    const int*   ei       = (const int*)  d_in[1];   // [2,E]: src row then dst row
    const int*   attr     = (const int*)  d_in[2];
    const float* edge_emb = (const float*)d_in[3];

    const float* c1_Wq = (const float*)d_in[4];  const float* c1_bq = (const float*)d_in[5];
    const float* c1_Wk = (const float*)d_in[6];  const float* c1_bk = (const float*)d_in[7];
    const float* c1_Wv = (const float*)d_in[8];  const float* c1_bv = (const float*)d_in[9];
    const float* c1_We = (const float*)d_in[10];
    const float* c1_Ws = (const float*)d_in[11]; const float* c1_bs = (const float*)d_in[12];

    const float* c2_Wq = (const float*)d_in[13]; const float* c2_bq = (const float*)d_in[14];
    const float* c2_Wk = (const float*)d_in[15]; const float* c2_bk = (const float*)d_in[16];
    const float* c2_Wv = (const float*)d_in[17]; const float* c2_bv = (const float*)d_in[18];
    const float* c2_We = (const float*)d_in[19];
    const float* c2_Ws = (const float*)d_in[20]; const float* c2_bs = (const float*)d_in[21];

    const float* Wout = (const float*)d_in[22];
    const float* bout = (const float*)d_in[23];

    // -------- workspace carve-up --------
    float* w = (float*)d_ws;
    float* te1 = w;                         // 1024
    float* te2 = te1 + 1024;                // 1024
    float* Q   = te2 + 1024;                // N*64
    float* K   = Q  + N_NODES * 64;
    float* Vb  = K  + N_NODES * 64;
    float* S   = Vb + N_NODES * 64;
    float* H1  = S  + N_NODES * 64;         // conv out (conv2 aliases)
    int*   ip  = (int*)(H1 + N_NODES * 64);
    int* deg    = ip;                       // N
    int* loc    = deg + N_NODES;            // N
    int* bsum   = loc + N_NODES;            // NB_SCAN
    int* bpre   = bsum + NB_SCAN;           // NB_SCAN
    int* rowptr = bpre + NB_SCAN;           // N+1
    int* cursor = rowptr + N_NODES + 1;     // N
    int* bcur   = cursor + N_NODES;         // NBKT
    unsigned* epack = (unsigned*)(bcur + NBKT);       // E
    unsigned* ebin  = (unsigned*)H1;        // E, aliases H1 (dead until conv1 output)

    const int edge_blocks = (E_EDGES + 255) / 256;
    const int bin_blocks  = (E_EDGES + EPB - 1) / EPB;
    const int node_grp    = (N_NODES + 3) / 4;        // conv_node: 4 nodes/block
    const int gemm_blocks = (N_NODES + 31) / 32;      // qkvs: 32 rows/block

    // edge-type tables for both convs
    table_kernel<<<8, 256, 0, stream>>>(edge_emb, c1_We, c2_We, te1, te2);

    // -------- CSR build (two-pass binned counting sort by dst) --------
    zero_deg_kernel<<<NB_SCAN, 256, 0, stream>>>(deg);
    hist_kernel<<<edge_blocks, 256, 0, stream>>>(ei, deg);
    scan1_kernel<<<NB_SCAN, 256, 0, stream>>>(deg, loc, bsum);
    scan2_kernel<<<1, 256, 0, stream>>>(bsum, bpre);
    scan3_kernel<<<NB_SCAN, 256, 0, stream>>>(loc, bpre, rowptr, cursor, bcur);
    bin_kernel<<<bin_blocks, 256, 0, stream>>>(ei, attr, bcur, ebin);
    place_kernel<<<dim3(NBKT, 8), 256, 0, stream>>>(rowptr, ebin, cursor, epack);

    // -------- conv1 --------
    qkvs_kernel<F_IN><<<gemm_blocks, 256, 0, stream>>>(
        x, c1_Wq, c1_bq, c1_Wk, c1_bk, c1_Wv, c1_bv, c1_Ws, c1_bs, Q, K, Vb, S);
    conv_node_kernel<<<node_grp, 256, 0, stream>>>(rowptr, epack, Q, K, Vb, S, te1, H1);

    // -------- conv2 --------
    qkvs_kernel<H_DIM><<<gemm_blocks, 256, 0, stream>>>(
        H1, c2_Wq, c2_bq, c2_Wk, c2_bk, c2_Wv, c2_bv, c2_Ws, c2_bs, Q, K, Vb, S);
    conv_node_kernel<<<node_grp, 256, 0, stream>>>(rowptr, epack, Q, K, Vb, S, te2, H1);

    // -------- output projection --------
    out_kernel<<<(N_NODES + 15) / 16, 256, 0, stream>>>(H1, Wout, bout, (float*)d_out);
}

// Round 7
// 526.006 us; speedup vs baseline: 3.6121x; 1.1067x over previous
//
#include <hip/hip_runtime.h>
#include <math.h>

#define N_NODES 50000
#define E_EDGES 1600000
#define F_IN    128
#define H_DIM   64
#define V_SIZE  16
#define OUT_DIM 2
#define EPS_F   1e-16f

#define NB_SCAN 196   // ceil(50000/256)
#define NBKT    196   // coarse buckets (256 nodes each)
#define EPB     4096  // edges per bin_kernel block

// -------- bf16 helpers --------
__device__ __forceinline__ unsigned bf16r(float x) {
    unsigned u = __float_as_uint(x);
    return (u + 0x7FFFu + ((u >> 16) & 1u)) >> 16;       // RNE
}
__device__ __forceinline__ unsigned bf16pack(float lo, float hi) {
    return bf16r(lo) | (bf16r(hi) << 16);
}
__device__ __forceinline__ float bl(unsigned w) { return __uint_as_float(w << 16); }
__device__ __forceinline__ float bh(unsigned w) { return __uint_as_float(w & 0xFFFF0000u); }

// ---------------- te = edge_emb @ We  (two [16,64] tables) ----------------
__global__ void table_kernel(const float* __restrict__ edge_emb,
                             const float* __restrict__ We1,
                             const float* __restrict__ We2,
                             float* __restrict__ te1, float* __restrict__ te2) {
    int t = blockIdx.x * blockDim.x + threadIdx.x;   // 0..2047
    if (t >= 2 * V_SIZE * H_DIM) return;
    int which = t >> 10;
    int idx = t & 1023;
    int v = idx >> 6, h = idx & 63;
    const float* We = which ? We2 : We1;
    float* te = which ? te2 : te1;
    float acc = 0.f;
    for (int k = 0; k < H_DIM; ++k)
        acc += edge_emb[v * H_DIM + k] * We[k * H_DIM + h];
    te[idx] = acc;
}

// ---------------- CSR build: counting sort of edges by dst ----------------
__global__ void zero_deg_kernel(int* __restrict__ deg) {
    int i = blockIdx.x * blockDim.x + threadIdx.x;
    if (i < N_NODES) deg[i] = 0;
}

__global__ void hist_kernel(const int* __restrict__ ei, int* __restrict__ deg) {
    int e = blockIdx.x * blockDim.x + threadIdx.x;
    if (e >= E_EDGES) return;
    atomicAdd(&deg[ei[E_EDGES + e]], 1);
}

__global__ void scan1_kernel(const int* __restrict__ deg,
                             int* __restrict__ loc, int* __restrict__ bsum) {
    __shared__ int s[256];
    int i = blockIdx.x * 256 + threadIdx.x;
    int v = (i < N_NODES) ? deg[i] : 0;
    s[threadIdx.x] = v;
    __syncthreads();
    for (int off = 1; off < 256; off <<= 1) {
        int t = (threadIdx.x >= off) ? s[threadIdx.x - off] : 0;
        __syncthreads();
        s[threadIdx.x] += t;
        __syncthreads();
    }
    if (i < N_NODES) loc[i] = s[threadIdx.x] - v;   // exclusive
    if (threadIdx.x == 255) bsum[blockIdx.x] = s[255];
}

__global__ void scan2_kernel(const int* __restrict__ bsum, int* __restrict__ bpre) {
    __shared__ int s[256];
    int t = threadIdx.x;
    int v = (t < NB_SCAN) ? bsum[t] : 0;
    s[t] = v;
    __syncthreads();
    for (int off = 1; off < 256; off <<= 1) {
        int u = (t >= off) ? s[t - off] : 0;
        __syncthreads();
        s[t] += u;
        __syncthreads();
    }
    if (t < NB_SCAN) bpre[t] = s[t] - v;            // exclusive
}

__global__ void scan3_kernel(const int* __restrict__ loc, const int* __restrict__ bpre,
                             int* __restrict__ rowptr, int* __restrict__ cursor,
                             int* __restrict__ bcur) {
    int i = blockIdx.x * 256 + threadIdx.x;
    if (i < N_NODES) {
        int r = loc[i] + bpre[blockIdx.x];
        rowptr[i] = r;
        cursor[i] = r;
        if ((i & 255) == 0) bcur[i >> 8] = r;        // coarse-bucket base/cursor
    }
    if (i == 0) rowptr[N_NODES] = E_EDGES;
}

// -------- pass A: bin edges by dst>>8 --------
__global__ __launch_bounds__(256) void bin_kernel(const int* __restrict__ ei,
                                                  const int* __restrict__ attr,
                                                  int* __restrict__ bcur,
                                                  unsigned* __restrict__ ebin) {
    __shared__ unsigned skey[EPB];
    __shared__ unsigned char sbkt[EPB];
    __shared__ int hist[NBKT], base[NBKT];
    const int tid = threadIdx.x;
    for (int i = tid; i < NBKT; i += 256) hist[i] = 0;
    __syncthreads();
    const int e0 = blockIdx.x * EPB;
    for (int i = tid; i < EPB; i += 256) {
        int e = e0 + i;
        if (e < E_EDGES) {
            int src = ei[e], dst = ei[E_EDGES + e], a = attr[e];
            skey[i] = (unsigned)src | ((unsigned)a << 16) | ((unsigned)(dst & 255) << 20);
            int b = dst >> 8;
            sbkt[i] = (unsigned char)b;
            atomicAdd(&hist[b], 1);
        } else {
            sbkt[i] = 0xFF;
        }
    }
    __syncthreads();
    for (int i = tid; i < NBKT; i += 256) {
        int h = hist[i];
        base[i] = h ? atomicAdd(&bcur[i], h) : 0;
        hist[i] = 0;                                  // reuse as rank counter
    }
    __syncthreads();
    for (int i = tid; i < EPB; i += 256) {
        int b = sbkt[i];
        if (b != 0xFF) {
            int r = atomicAdd(&hist[b], 1);
            ebin[base[b] + r] = skey[i];
        }
    }
}

// -------- pass B: exact placement within 32KB bucket windows --------
__global__ __launch_bounds__(256) void place_kernel(const int* __restrict__ rowptr,
                                                    const unsigned* __restrict__ ebin,
                                                    int* __restrict__ cursor,
                                                    unsigned* __restrict__ epack) {
    int b = blockIdx.x;
    int n0 = b << 8;
    int n1 = n0 + 256; if (n1 > N_NODES) n1 = N_NODES;
    int bstart = rowptr[n0], bend = rowptr[n1];
    for (int e = bstart + blockIdx.y * 256 + threadIdx.x; e < bend; e += 256 * 8) {
        unsigned p = ebin[e];
        int dst = n0 + (int)((p >> 20) & 255u);
        int pos = atomicAdd(&cursor[dst], 1);
        epack[pos] = p;                               // src:16 | attr:4
    }
}

// ------- fused Q/K/V/Skip GEMM; K,V emitted as packed bf16 -------
template <int DIN>
__global__ __launch_bounds__(256) void qkvs_kernel(
        const float* __restrict__ X,
        const float* __restrict__ Wq, const float* __restrict__ bq,
        const float* __restrict__ Wk, const float* __restrict__ bk,
        const float* __restrict__ Wv, const float* __restrict__ bv,
        const float* __restrict__ Ws, const float* __restrict__ bs,
        float* __restrict__ Q, unsigned* __restrict__ KVh,
        float* __restrict__ S) {
    __shared__ float xs[32][DIN];
    const int row0 = blockIdx.x * 32;
    const int tid = threadIdx.x;
    const int f4_per_row = DIN / 4;
    const int nf4 = 32 * f4_per_row;
    for (int i = tid; i < nf4; i += 256) {
        int row = row0 + i / f4_per_row;
        float4 v = make_float4(0.f, 0.f, 0.f, 0.f);
        if (row < N_NODES) v = ((const float4*)X)[(size_t)row0 * f4_per_row + i];
        ((float4*)&xs[0][0])[i] = v;
    }
    __syncthreads();
    const int c = tid & 63;        // output column
    const int w = tid >> 6;        // wave id: rows w, w+4, ..., w+28
    float aq[8], ak[8], av[8], as_[8];
    float bq_ = bq[c], bk_ = bk[c], bv_ = bv[c], bs_ = bs[c];
    #pragma unroll
    for (int j = 0; j < 8; ++j) { aq[j] = bq_; ak[j] = bk_; av[j] = bv_; as_[j] = bs_; }
    #pragma unroll 2
    for (int k = 0; k < DIN; ++k) {
        float wq = Wq[k * 64 + c], wk = Wk[k * 64 + c];
        float wv = Wv[k * 64 + c], ws = Ws[k * 64 + c];
        #pragma unroll
        for (int j = 0; j < 8; ++j) {
            float xv = xs[w + j * 4][k];
            aq[j]  = fmaf(xv, wq, aq[j]);
            ak[j]  = fmaf(xv, wk, ak[j]);
            av[j]  = fmaf(xv, wv, av[j]);
            as_[j] = fmaf(xv, ws, as_[j]);
        }
    }
    #pragma unroll
    for (int j = 0; j < 8; ++j) {
        int row = row0 + w + j * 4;             // uniform across wave
        if (row < N_NODES) {
            Q[row * 64 + c] = aq[j];
            S[row * 64 + c] = as_[j];
            float kn = __shfl_down(ak[j], 1);
            float vn = __shfl_down(av[j], 1);
            if (!(c & 1)) {
                KVh[row * 64 + (c >> 1)]      = bf16pack(ak[j], kn);
                KVh[row * 64 + 32 + (c >> 1)] = bf16pack(av[j], vn);
            }
        }
    }
}

// ------- per-node attention: 8 edges/wave, bf16 K/V, qte-folded edge term -------
__global__ __launch_bounds__(256) void conv_node_kernel(
        const int* __restrict__ rowptr, const unsigned* __restrict__ epack,
        const unsigned* __restrict__ KVh, const float* __restrict__ Qf,
        const float* __restrict__ S, const float* __restrict__ te,
        float* __restrict__ Hout) {
    __shared__ float4 tes4[V_SIZE * 16];    // te as float4 rows: [a*16 + ch/4]
    __shared__ float qte_s[4][16];
    for (int i = threadIdx.x; i < V_SIZE * 16; i += 256)
        tes4[i] = ((const float4*)te)[i];
    __syncthreads();
    const int wv = threadIdx.x >> 6;
    const int node = blockIdx.x * 4 + wv;
    if (node >= N_NODES) return;
    const int lane = threadIdx.x & 63;
    const int g  = lane >> 3;      // edge slot (8 concurrent edges)
    const int lo = lane & 7;       // channel octet: ch = lo*8 .. lo*8+7
    const int e0 = rowptr[node], e1 = rowptr[node + 1];
    float4 qa = ((const float4*)Qf)[node * 16 + lo * 2];
    float4 qb = ((const float4*)Qf)[node * 16 + lo * 2 + 1];
    // prologue: qte_s[wv][a] = 0.125 * q . te_a   (folds edge term out of K path)
    #pragma unroll 4
    for (int a = 0; a < 16; ++a) {
        float4 ta = tes4[a * 16 + lo * 2];
        float4 tb = tes4[a * 16 + lo * 2 + 1];
        float t = qa.x * ta.x + qa.y * ta.y + qa.z * ta.z + qa.w * ta.w
                + qb.x * tb.x + qb.y * tb.y + qb.z * tb.z + qb.w * tb.w;
        t += __shfl_xor(t, 1); t += __shfl_xor(t, 2); t += __shfl_xor(t, 4);
        if (lane == 0) qte_s[wv][a] = t * 0.125f;
    }
    float acc[8] = {0.f, 0.f, 0.f, 0.f, 0.f, 0.f, 0.f, 0.f};
    float den = 0.f;
    const uint4* KV4 = (const uint4*)KVh;   // node row = 16 uint4 (8 K + 8 V)
    for (int eb = e0; eb < e1; eb += 8) {
        int e = eb + g;
        bool valid = e < e1;
        unsigned p = valid ? epack[e] : 0u;
        int src = p & 0xFFFF;
        int a = (p >> 16) & 15;
        uint4 kw = KV4[src * 16 + lo];
        float t = qa.x * bl(kw.x) + qa.y * bh(kw.x)
                + qa.z * bl(kw.y) + qa.w * bh(kw.y)
                + qb.x * bl(kw.z) + qb.y * bh(kw.z)
                + qb.z * bl(kw.w) + qb.w * bh(kw.w);
        t += __shfl_xor(t, 1); t += __shfl_xor(t, 2); t += __shfl_xor(t, 4);
        float ea = valid ? __expf(fmaf(t, 0.125f, qte_s[wv][a])) : 0.f;
        uint4 vw = KV4[src * 16 + 8 + lo];
        float4 ta = tes4[a * 16 + lo * 2];
        float4 tb = tes4[a * 16 + lo * 2 + 1];
        acc[0] = fmaf(ea, bl(vw.x) + ta.x, acc[0]);
        acc[1] = fmaf(ea, bh(vw.x) + ta.y, acc[1]);
        acc[2] = fmaf(ea, bl(vw.y) + ta.z, acc[2]);
        acc[3] = fmaf(ea, bh(vw.y) + ta.w, acc[3]);
        acc[4] = fmaf(ea, bl(vw.z) + tb.x, acc[4]);
        acc[5] = fmaf(ea, bh(vw.z) + tb.y, acc[5]);
        acc[6] = fmaf(ea, bl(vw.w) + tb.z, acc[6]);
        acc[7] = fmaf(ea, bh(vw.w) + tb.w, acc[7]);
        den += ea;
    }
    // reduce across the 8 edge slots
    #pragma unroll
    for (int off = 8; off < 64; off <<= 1) {
        #pragma unroll
        for (int i = 0; i < 8; ++i) acc[i] += __shfl_xor(acc[i], off);
        den += __shfl_xor(den, off);
    }
    if (g == 0) {
        float inv = 1.f / (den + EPS_F);
        float4 sa = ((const float4*)S)[node * 16 + lo * 2];
        float4 sb = ((const float4*)S)[node * 16 + lo * 2 + 1];
        float4 oa, ob;
        oa.x = fmaxf(fmaf(acc[0], inv, sa.x), 0.f);
        oa.y = fmaxf(fmaf(acc[1], inv, sa.y), 0.f);
        oa.z = fmaxf(fmaf(acc[2], inv, sa.z), 0.f);
        oa.w = fmaxf(fmaf(acc[3], inv, sa.w), 0.f);
        ob.x = fmaxf(fmaf(acc[4], inv, sb.x), 0.f);
        ob.y = fmaxf(fmaf(acc[5], inv, sb.y), 0.f);
        ob.z = fmaxf(fmaf(acc[6], inv, sb.z), 0.f);
        ob.w = fmaxf(fmaf(acc[7], inv, sb.w), 0.f);
        ((float4*)Hout)[node * 16 + lo * 2] = oa;
        ((float4*)Hout)[node * 16 + lo * 2 + 1] = ob;
    }
}

// ---------------- final projection: 16 lanes per node, coalesced ----------------
__global__ void out_kernel(const float* __restrict__ Hf,
                           const float* __restrict__ Wout,
                           const float* __restrict__ bout,
                           float* __restrict__ out) {
    int node = blockIdx.x * 16 + (threadIdx.x >> 4);
    if (node >= N_NODES) return;
    int lq = threadIdx.x & 15;
    float4 h = ((const float4*)Hf)[node * 16 + lq];
    int k0 = lq * 4;
    float p0 = h.x * Wout[(k0 + 0) * 2] + h.y * Wout[(k0 + 1) * 2]
             + h.z * Wout[(k0 + 2) * 2] + h.w * Wout[(k0 + 3) * 2];
    float p1 = h.x * Wout[(k0 + 0) * 2 + 1] + h.y * Wout[(k0 + 1) * 2 + 1]
             + h.z * Wout[(k0 + 2) * 2 + 1] + h.w * Wout[(k0 + 3) * 2 + 1];
    #pragma unroll
    for (int off = 1; off < 16; off <<= 1) {
        p0 += __shfl_xor(p0, off);
        p1 += __shfl_xor(p1, off);
    }
    if (lq == 0) {
        out[node * 2 + 0] = p0 + bout[0];
        out[node * 2 + 1] = p1 + bout[1];
    }
}

extern "C" void kernel_launch(void* const* d_in, const int* in_sizes, int n_in,
                              void* d_out, int out_size, void* d_ws, size_t ws_size,
                              hipStream_t stream) {
    const float* x        = (const float*)d_in[0];
    const int*   ei       = (const int*)  d_in[1];   // [2,E]: src row then dst row
    const int*   attr     = (const int*)  d_in[2];
    const float* edge_emb = (const float*)d_in[3];

    const float* c1_Wq = (const float*)d_in[4];  const float* c1_bq = (const float*)d_in[5];
    const float* c1_Wk = (const float*)d_in[6];  const float* c1_bk = (const float*)d_in[7];
    const float* c1_Wv = (const float*)d_in[8];  const float* c1_bv = (const float*)d_in[9];
    const float* c1_We = (const float*)d_in[10];
    const float* c1_Ws = (const float*)d_in[11]; const float* c1_bs = (const float*)d_in[12];

    const float* c2_Wq = (const float*)d_in[13]; const float* c2_bq = (const float*)d_in[14];
    const float* c2_Wk = (const float*)d_in[15]; const float* c2_bk = (const float*)d_in[16];
    const float* c2_Wv = (const float*)d_in[17]; const float* c2_bv = (const float*)d_in[18];
    const float* c2_We = (const float*)d_in[19];
    const float* c2_Ws = (const float*)d_in[20]; const float* c2_bs = (const float*)d_in[21];

    const float* Wout = (const float*)d_in[22];
    const float* bout = (const float*)d_in[23];

    // -------- workspace carve-up --------
    float* w = (float*)d_ws;
    float* te1 = w;                         // 1024
    float* te2 = te1 + 1024;                // 1024
    float* Q   = te2 + 1024;                // N*64 f32
    float* S   = Q  + N_NODES * 64;         // N*64 f32
    float* H1  = S  + N_NODES * 64;         // N*64 f32 (conv out; ebin aliases pre-conv1)
    unsigned* KVh = (unsigned*)(H1 + N_NODES * 64);   // N*64 u32 (bf16 K|V)
    int* deg    = (int*)(KVh + N_NODES * 64);          // N
    int* loc    = deg + N_NODES;            // N
    int* bsum   = loc + N_NODES;            // NB_SCAN
    int* bpre   = bsum + NB_SCAN;           // NB_SCAN
    int* rowptr = bpre + NB_SCAN;           // N+1
    int* cursor = rowptr + N_NODES + 1;     // N
    int* bcur   = cursor + N_NODES;         // NBKT
    unsigned* epack = (unsigned*)(bcur + NBKT);       // E
    unsigned* ebin  = (unsigned*)H1;        // E, aliases H1 (dead until conv1 output)

    const int edge_blocks = (E_EDGES + 255) / 256;
    const int bin_blocks  = (E_EDGES + EPB - 1) / EPB;
    const int node_grp    = (N_NODES + 3) / 4;        // conv_node: 4 nodes/block
    const int gemm_blocks = (N_NODES + 31) / 32;      // qkvs: 32 rows/block

    // edge-type tables for both convs
    table_kernel<<<8, 256, 0, stream>>>(edge_emb, c1_We, c2_We, te1, te2);

    // -------- CSR build (two-pass binned counting sort by dst) --------
    zero_deg_kernel<<<NB_SCAN, 256, 0, stream>>>(deg);
    hist_kernel<<<edge_blocks, 256, 0, stream>>>(ei, deg);
    scan1_kernel<<<NB_SCAN, 256, 0, stream>>>(deg, loc, bsum);
    scan2_kernel<<<1, 256, 0, stream>>>(bsum, bpre);
    scan3_kernel<<<NB_SCAN, 256, 0, stream>>>(loc, bpre, rowptr, cursor, bcur);
    bin_kernel<<<bin_blocks, 256, 0, stream>>>(ei, attr, bcur, ebin);
    place_kernel<<<dim3(NBKT, 8), 256, 0, stream>>>(rowptr, ebin, cursor, epack);

    // -------- conv1 --------
    qkvs_kernel<F_IN><<<gemm_blocks, 256, 0, stream>>>(
        x, c1_Wq, c1_bq, c1_Wk, c1_bk, c1_Wv, c1_bv, c1_Ws, c1_bs, Q, KVh, S);
    conv_node_kernel<<<node_grp, 256, 0, stream>>>(rowptr, epack, KVh, Q, S, te1, H1);

    // -------- conv2 --------
    qkvs_kernel<H_DIM><<<gemm_blocks, 256, 0, stream>>>(
        H1, c2_Wq, c2_bq, c2_Wk, c2_bk, c2_Wv, c2_bv, c2_Ws, c2_bs, Q, KVh, S);
    conv_node_kernel<<<node_grp, 256, 0, stream>>>(rowptr, epack, KVh, Q, S, te2, H1);

    // -------- output projection --------
    out_kernel<<<(N_NODES + 15) / 16, 256, 0, stream>>>(H1, Wout, bout, (float*)d_out);
}